// Round 6
// baseline (440.534 us; speedup 1.0000x reference)
//
#include <hip/hip_runtime.h>
#include <hip/hip_fp16.h>
#include <math.h>

constexpr int N = 100000;   // nodes
constexpr int E = 1600000;  // edges
constexpr int F = 32;       // F_IN == HIDDEN
constexpr int C = 2;        // classes

constexpr int NBUCK = (N + 511) >> 9;           // 196 buckets of 512 dst nodes
constexpr int CAPB  = 10240;                    // padded bucket capacity (mean 8163, +23 sigma)
constexpr int CHUNK = 8192;                     // edges per redistribution WG
constexpr int NCHUNK = (E + CHUNK - 1) / CHUNK; // 196

__device__ __forceinline__ int get_src(const int* ei, int e, int f64) {
    return f64 ? ei[2 * e] : ei[e];
}
__device__ __forceinline__ int get_dst(const int* ei, int e, int f64) {
    return f64 ? ei[2 * (E + e)] : ei[E + e];
}

// ---------------------------------------------------------------------------
// Bucket redistribution with built-in int64/int32 layout probe (each WG reads
// the same first 2048 odd dwords; all-zero <=> int64 little-endian). Edges go
// to padded bucket-major packed (local_dst<<17 | src) slots; one global atomic
// per (WG, bucket).
// ---------------------------------------------------------------------------
__global__ void k_bucket(const int* __restrict__ ei, int* __restrict__ bcursor,
                         int* __restrict__ epk) {
    __shared__ int h[NBUCK];
    __shared__ int base[NBUCK];
    __shared__ int sflag;
    int tid = threadIdx.x;
    if (tid == 0) sflag = 0;
    for (int i = tid; i < NBUCK; i += blockDim.x) h[i] = 0;
    __syncthreads();
    int accf = 0;
    for (int i = tid; i < 2048; i += blockDim.x) accf |= ei[2 * i + 1];
    if (accf) atomicOr(&sflag, 1);
    __syncthreads();
    int f64 = sflag ? 0 : 1;
    int e0 = blockIdx.x * CHUNK;
    int e1 = min(E, e0 + CHUNK);
    for (int e = e0 + tid; e < e1; e += blockDim.x)
        atomicAdd(&h[get_dst(ei, e, f64) >> 9], 1);
    __syncthreads();
    for (int b = tid; b < NBUCK; b += blockDim.x) {
        if (h[b] > 0) base[b] = atomicAdd(&bcursor[b], h[b]);
        h[b] = 0;  // reuse as local rank counter
    }
    __syncthreads();
    for (int e = e0 + tid; e < e1; e += blockDim.x) {
        int s = get_src(ei, e, f64);
        int d = get_dst(ei, e, f64);
        int b = d >> 9;
        int r = atomicAdd(&h[b], 1);
        int pos = base[b] + r;
        if (pos < CAPB)  // memory-safety clamp; never taken for this input
            epk[b * CAPB + pos] = ((d & 511) << 17) | s;
    }
}

// Per-bucket degree histogram -> dis = rsqrt(deg+1).
__global__ __launch_bounds__(512) void k_dis(const int* __restrict__ epk,
                                             const int* __restrict__ bcursor,
                                             float* __restrict__ dis) {
    __shared__ int hcnt[512];
    int b = blockIdx.x, tid = threadIdx.x;
    hcnt[tid] = 0;
    __syncthreads();
    int cnt = min(bcursor[b], CAPB);
    const int* e = epk + b * CAPB;
    for (int i = tid; i < cnt; i += 512)
        atomicAdd(&hcnt[e[i] >> 17], 1);
    __syncthreads();
    int n = (b << 9) + tid;
    if (n < N) dis[n] = rsqrtf((float)(hcnt[tid] + 1));  // +1 self-loop
}

// t1h[i][f] = fp16( (x[i] @ W1)[f] * dis[i] ).  32 lanes per node; x row
// loaded coalesced (1 float/lane) and broadcast via shfl.
__global__ void k_xw1(const float* __restrict__ x, const float* __restrict__ W1,
                      const float* __restrict__ dis, __half* __restrict__ t1h) {
    __shared__ float W1s[F * F];
    int tid = threadIdx.x;
    for (int i = tid; i < F * F; i += blockDim.x) W1s[i] = W1[i];
    __syncthreads();
    int lane = tid & 31;
    int node = (blockIdx.x * blockDim.x + tid) >> 5;
    if (node >= N) return;
    float xv = x[node * F + lane];
    float acc = 0.f;
#pragma unroll
    for (int k = 0; k < F; ++k) acc += __shfl(xv, k, 32) * W1s[k * F + lane];
    float v = acc * dis[node];
    float o = __shfl_xor(v, 1, 32);
    if (!(lane & 1))
        ((__half2*)t1h)[node * 16 + (lane >> 1)] = __floats2half2_rn(v, o);
}

// Layer-1 aggregation straight from bucket-major epk into a 64KB LDS
// accumulator acc[f][ld] (bank = ld%32: random ~2-way conflicts). One thread
// per edge: 4 independent 16B gathers + 32 ds_add_f32. Finalize fuses
// self-loop + dis + bias + relu + W2 -> t2.
__global__ __launch_bounds__(512) void k_agg1f(
        const int* __restrict__ epk, const int* __restrict__ bcursor,
        const __half* __restrict__ t1h, const float* __restrict__ dis,
        const float* __restrict__ b1, const float* __restrict__ W2,
        float* __restrict__ t2) {
    __shared__ float acc[F * 512];  // exactly 64 KB
    int b = blockIdx.x, tid = threadIdx.x;
    for (int i = tid; i < F * 512; i += 512) acc[i] = 0.f;
    __syncthreads();
    int cnt = min(bcursor[b], CAPB);
    const int* e = epk + b * CAPB;
    for (int i = tid; i < cnt; i += 512) {
        int p = e[i];
        int s = p & 0x1FFFF;
        int ld = p >> 17;
        const float4* row = (const float4*)(t1h + s * F);
        float4 w0 = row[0], w1 = row[1], w2 = row[2], w3 = row[3];
#define ACC8(w, fb)                                                         \
        {                                                                   \
            const __half2* hp = (const __half2*)&(w);                       \
            _Pragma("unroll")                                               \
            for (int q = 0; q < 4; ++q) {                                   \
                float2 f = __half22float2(hp[q]);                           \
                atomicAdd(&acc[((fb) + 2 * q) * 512 + ld], f.x);            \
                atomicAdd(&acc[((fb) + 2 * q + 1) * 512 + ld], f.y);        \
            }                                                               \
        }
        ACC8(w0, 0) ACC8(w1, 8) ACC8(w2, 16) ACC8(w3, 24)
#undef ACC8
    }
    __syncthreads();
    int node = (b << 9) + tid;
    if (node < N) {
        float d = dis[node];
        const __half2* self = (const __half2*)(t1h + node * F);
        float p0 = 0.f, p1 = 0.f;
#pragma unroll
        for (int f2 = 0; f2 < 16; ++f2) {
            float2 sv = __half22float2(self[f2]);
            float h0 = fmaxf(d * (acc[(2 * f2) * 512 + tid] + sv.x) + b1[2 * f2], 0.f);
            float h1 = fmaxf(d * (acc[(2 * f2 + 1) * 512 + tid] + sv.y) + b1[2 * f2 + 1], 0.f);
            p0 += h0 * W2[(2 * f2) * C + 0] + h1 * W2[(2 * f2 + 1) * C + 0];
            p1 += h0 * W2[(2 * f2) * C + 1] + h1 * W2[(2 * f2 + 1) * C + 1];
        }
        float2 o;
        o.x = p0 * d;
        o.y = p1 * d;
        *(float2*)(t2 + node * C) = o;
    }
}

// Layer-2 aggregation from epk with 4KB LDS accumulator + log_softmax.
__global__ __launch_bounds__(512) void k_agg2f(
        const int* __restrict__ epk, const int* __restrict__ bcursor,
        const float* __restrict__ t2, const float* __restrict__ dis,
        const float* __restrict__ b2, float* __restrict__ out) {
    __shared__ float a0[512];
    __shared__ float a1[512];
    int b = blockIdx.x, tid = threadIdx.x;
    a0[tid] = 0.f;
    a1[tid] = 0.f;
    __syncthreads();
    int cnt = min(bcursor[b], CAPB);
    const int* e = epk + b * CAPB;
    for (int i = tid; i < cnt; i += 512) {
        int p = e[i];
        int s = p & 0x1FFFF;
        int ld = p >> 17;
        float2 v = *(const float2*)(t2 + s * C);
        atomicAdd(&a0[ld], v.x);
        atomicAdd(&a1[ld], v.y);
    }
    __syncthreads();
    int node = (b << 9) + tid;
    if (node < N) {
        float d = dis[node];
        float2 self = *(const float2*)(t2 + node * C);
        float z0 = d * (a0[tid] + self.x) + b2[0];
        float z1 = d * (a1[tid] + self.y) + b2[1];
        float m = fmaxf(z0, z1);
        float l = m + logf(expf(z0 - m) + expf(z1 - m));
        float2 o;
        o.x = z0 - l;
        o.y = z1 - l;
        *(float2*)(out + node * C) = o;
    }
}

extern "C" void kernel_launch(void* const* d_in, const int* in_sizes, int n_in,
                              void* d_out, int out_size, void* d_ws, size_t ws_size,
                              hipStream_t stream) {
    const float* x  = (const float*)d_in[0];
    const int*   ei = (const int*)d_in[1];
    const float* W1 = (const float*)d_in[2];
    const float* b1 = (const float*)d_in[3];
    const float* W2 = (const float*)d_in[4];
    const float* b2 = (const float*)d_in[5];
    float* out = (float*)d_out;

    // Workspace (4B units): epk[NBUCK*CAPB] | t1h[N*F halves] | dis[N] |
    // t2[N*C] | bcursor[NBUCK]
    int* ws_i = (int*)d_ws;
    int*    epk     = ws_i;
    __half* t1h     = (__half*)(epk + (size_t)NBUCK * CAPB);
    float*  dis     = (float*)(t1h + (size_t)N * F);
    float*  t2      = dis + N;
    int*    bcursor = (int*)(t2 + (size_t)N * C);

    const int B = 256;
    hipMemsetAsync(bcursor, 0, NBUCK * sizeof(int), stream);
    k_bucket<<<NCHUNK, B, 0, stream>>>(ei, bcursor, epk);
    k_dis<<<NBUCK, 512, 0, stream>>>(epk, bcursor, dis);
    k_xw1<<<(N * 32 + B - 1) / B, B, 0, stream>>>(x, W1, dis, t1h);
    k_agg1f<<<NBUCK, 512, 0, stream>>>(epk, bcursor, t1h, dis, b1, W2, t2);
    k_agg2f<<<NBUCK, 512, 0, stream>>>(epk, bcursor, t2, dis, b2, out);
}

// Round 8
// 109.862 us; speedup vs baseline: 4.0099x; 4.0099x over previous
//
#include <hip/hip_runtime.h>
#include <hip/hip_fp16.h>
#include <math.h>

constexpr int N = 100000;   // nodes
constexpr int E = 1600000;  // edges
constexpr int F = 32;       // F_IN == HIDDEN
constexpr int C = 2;        // classes

constexpr int NBUCK = (N + 511) >> 9;           // 196 buckets of 512 dst nodes
constexpr int CAPB  = 10240;                    // padded per-bucket capacity
                                                // (mean 8163, sigma ~90 -> +23 sigma)
constexpr int CHUNK = 8192;                     // edges per redistribution WG
constexpr int NCHUNK = (E + CHUNK - 1) / CHUNK; // 196

// ---------------------------------------------------------------------------
// Edge-index format probe (int64 vs int32) + zero bucket cursors.
// int64 little-endian with values < 2^31 -> every odd dword is 0.
// ---------------------------------------------------------------------------
__global__ void k_detect(const int* __restrict__ ei, int* __restrict__ flag,
                         int* __restrict__ bcursor) {
    __shared__ int any;
    if (threadIdx.x == 0) any = 0;
    __syncthreads();
    int acc = 0;
    for (int i = threadIdx.x; i < 2048; i += blockDim.x)
        acc |= ei[2 * i + 1];
    if (acc) atomicOr(&any, 1);
    for (int i = threadIdx.x; i < NBUCK; i += blockDim.x) bcursor[i] = 0;
    __syncthreads();
    if (threadIdx.x == 0) flag[0] = any ? 0 : 1;
}

__device__ __forceinline__ int get_src(const int* ei, int e, int f64) {
    return f64 ? ei[2 * e] : ei[e];
}
__device__ __forceinline__ int get_dst(const int* ei, int e, int f64) {
    return f64 ? ei[2 * (E + e)] : ei[E + e];
}

// Redistribute edges into padded bucket-major packed (local_dst<<17 | src)
// array. Chunk is staged in LDS (one global read), histogrammed, then written
// from LDS. One global atomic per (WG, bucket).
__global__ void k_bucket(const int* __restrict__ ei, int* __restrict__ bcursor,
                         int* __restrict__ epk, const int* __restrict__ flag) {
    __shared__ int h[NBUCK];
    __shared__ int base[NBUCK];
    __shared__ int sS[CHUNK];
    __shared__ int sD[CHUNK];
    int tid = threadIdx.x;
    for (int i = tid; i < NBUCK; i += blockDim.x) h[i] = 0;
    __syncthreads();
    int f64 = flag[0];
    int e0 = blockIdx.x * CHUNK;
    int ne = min(E - e0, CHUNK);
    for (int i = tid; i < ne; i += blockDim.x) {
        int s = get_src(ei, e0 + i, f64);
        int d = get_dst(ei, e0 + i, f64);
        sS[i] = s;
        sD[i] = d;
        atomicAdd(&h[d >> 9], 1);
    }
    __syncthreads();
    for (int b = tid; b < NBUCK; b += blockDim.x) {
        if (h[b] > 0) base[b] = atomicAdd(&bcursor[b], h[b]);
        h[b] = 0;  // reuse as local rank counter
    }
    __syncthreads();
    for (int i = tid; i < ne; i += blockDim.x) {
        int d = sD[i];
        int b = d >> 9;
        int r = atomicAdd(&h[b], 1);
        int pos = base[b] + r;
        if (pos < CAPB)  // memory-safety clamp; never taken for this input
            epk[b * CAPB + pos] = ((d & 511) << 17) | sS[i];
    }
}

// Per-bucket CSR finalize: per-node counts+scan in LDS, rs/re & dis out,
// LDS-staged col segment, coalesced copy-out into padded col array.
__global__ __launch_bounds__(512) void k_csr(
        const int* __restrict__ epk, const int* __restrict__ bcursor,
        int* __restrict__ rs, int* __restrict__ re,
        float* __restrict__ dis, int* __restrict__ colp) {
    __shared__ int hcnt[512];
    __shared__ int s[512];
    __shared__ int lcur[512];
    __shared__ int colseg[CAPB];
    int b = blockIdx.x;
    int tid = threadIdx.x;
    int n0 = b << 9;
    int nn = min(512, N - n0);
    int cbase = b * CAPB;
    int cnt = min(bcursor[b], CAPB);
    hcnt[tid] = 0;
    __syncthreads();
    for (int i = tid; i < cnt; i += 512)
        atomicAdd(&hcnt[epk[cbase + i] >> 17], 1);
    __syncthreads();
    s[tid] = hcnt[tid];
    __syncthreads();
    for (int off = 1; off < 512; off <<= 1) {
        int t = (tid >= off) ? s[tid - off] : 0;
        __syncthreads();
        s[tid] += t;
        __syncthreads();
    }
    int excl = s[tid] - hcnt[tid];
    lcur[tid] = excl;
    if (tid < nn) {
        rs[n0 + tid] = cbase + excl;
        re[n0 + tid] = cbase + excl + hcnt[tid];
        dis[n0 + tid] = rsqrtf((float)(hcnt[tid] + 1));  // +1 self-loop
    }
    __syncthreads();
    for (int i = tid; i < cnt; i += 512) {
        int p = epk[cbase + i];
        int r = atomicAdd(&lcur[p >> 17], 1);
        colseg[r] = p & 0x1FFFF;
    }
    __syncthreads();
    for (int i = tid; i < cnt; i += 512) colp[cbase + i] = colseg[i];
}

// t1h[i][f] = fp16( (x[i] @ W1)[f] * dis[i] ).  32 lanes per node; x row is
// loaded coalesced (1 float/lane) and broadcast via shfl.
__global__ void k_xw1(const float* __restrict__ x, const float* __restrict__ W1,
                      const float* __restrict__ dis, __half* __restrict__ t1h) {
    __shared__ float W1s[F * F];
    int tid = threadIdx.x;
    for (int i = tid; i < F * F; i += blockDim.x) W1s[i] = W1[i];
    __syncthreads();
    int lane = tid & 31;
    int node = (blockIdx.x * blockDim.x + tid) >> 5;
    if (node >= N) return;
    float xv = x[node * F + lane];
    float acc = 0.f;
#pragma unroll
    for (int k = 0; k < F; ++k) acc += __shfl(xv, k, 32) * W1s[k * F + lane];
    float v = acc * dis[node];
    float o = __shfl_xor(v, 1, 32);
    if (!(lane & 1))
        ((__half2*)t1h)[node * 16 + (lane >> 1)] = __floats2half2_rn(v, o);
}

// Accumulate one 16B row-slice of fp16 (8 halves) into two float4 accs.
__device__ __forceinline__ void acc8(float4& lo, float4& hi, const float4& r) {
    const __half2* hp = (const __half2*)&r;
    float2 f0 = __half22float2(hp[0]);
    float2 f1 = __half22float2(hp[1]);
    float2 f2 = __half22float2(hp[2]);
    float2 f3 = __half22float2(hp[3]);
    lo.x += f0.x; lo.y += f0.y; lo.z += f1.x; lo.w += f1.y;
    hi.x += f2.x; hi.y += f2.y; hi.z += f3.x; hi.w += f3.y;
}

// Layer-1 aggregation fused with relu/bias and h@W2. 4 lanes per node; each
// lane owns 8 features (one 16B float4 of fp16). 16 nodes/wave x 4-deep
// unroll -> up to 64 cache lines in flight per wave.
__global__ void k_agg1(const int* __restrict__ rs, const int* __restrict__ re,
                       const int* __restrict__ colp, const __half* __restrict__ t1h,
                       const float* __restrict__ dis, const float* __restrict__ b1,
                       const float* __restrict__ W2, float* __restrict__ t2) {
    int tid = blockIdx.x * blockDim.x + threadIdx.x;
    int node = tid >> 2;
    if (node >= N) return;
    int lane = tid & 3;
    const float4* t1v = (const float4*)t1h;  // 4 float4 (= 8 halves each) per row
    int start = rs[node], end = re[node];
    float4 lo0 = {0,0,0,0}, hi0 = {0,0,0,0};
    float4 lo1 = {0,0,0,0}, hi1 = {0,0,0,0};
    float4 lo2 = {0,0,0,0}, hi2 = {0,0,0,0};
    float4 lo3 = {0,0,0,0}, hi3 = {0,0,0,0};
    for (int base = start; base < end; base += 4) {
        int idx = base + lane;
        int sv = (idx < end) ? colp[idx] : 0;
        int cnt = end - base;
        if (cnt >= 4) {
            int i0 = __shfl(sv, 0, 4);
            int i1 = __shfl(sv, 1, 4);
            int i2 = __shfl(sv, 2, 4);
            int i3 = __shfl(sv, 3, 4);
            float4 r0 = t1v[i0 * 4 + lane];
            float4 r1 = t1v[i1 * 4 + lane];
            float4 r2 = t1v[i2 * 4 + lane];
            float4 r3 = t1v[i3 * 4 + lane];
            acc8(lo0, hi0, r0);
            acc8(lo1, hi1, r1);
            acc8(lo2, hi2, r2);
            acc8(lo3, hi3, r3);
        } else {
            for (int j = 0; j < cnt; ++j) {
                int ss = __shfl(sv, j, 4);
                float4 r = t1v[ss * 4 + lane];
                acc8(lo0, hi0, r);
            }
        }
    }
    float4 alo, ahi;
    alo.x = (lo0.x + lo1.x) + (lo2.x + lo3.x);
    alo.y = (lo0.y + lo1.y) + (lo2.y + lo3.y);
    alo.z = (lo0.z + lo1.z) + (lo2.z + lo3.z);
    alo.w = (lo0.w + lo1.w) + (lo2.w + lo3.w);
    ahi.x = (hi0.x + hi1.x) + (hi2.x + hi3.x);
    ahi.y = (hi0.y + hi1.y) + (hi2.y + hi3.y);
    ahi.z = (hi0.z + hi1.z) + (hi2.z + hi3.z);
    ahi.w = (hi0.w + hi1.w) + (hi2.w + hi3.w);
    float4 wself = t1v[node * 4 + lane];
    const __half2* sp = (const __half2*)&wself;
    float2 s0 = __half22float2(sp[0]);
    float2 s1 = __half22float2(sp[1]);
    float2 s2 = __half22float2(sp[2]);
    float2 s3 = __half22float2(sp[3]);
    float d = dis[node];
    int f0 = 8 * lane;
    float4 b1lo = *(const float4*)(b1 + f0);
    float4 b1hi = *(const float4*)(b1 + f0 + 4);
    float h0 = fmaxf(d * (alo.x + s0.x) + b1lo.x, 0.f);
    float h1 = fmaxf(d * (alo.y + s0.y) + b1lo.y, 0.f);
    float h2 = fmaxf(d * (alo.z + s1.x) + b1lo.z, 0.f);
    float h3 = fmaxf(d * (alo.w + s1.y) + b1lo.w, 0.f);
    float h4 = fmaxf(d * (ahi.x + s2.x) + b1hi.x, 0.f);
    float h5 = fmaxf(d * (ahi.y + s2.y) + b1hi.y, 0.f);
    float h6 = fmaxf(d * (ahi.z + s3.x) + b1hi.z, 0.f);
    float h7 = fmaxf(d * (ahi.w + s3.y) + b1hi.w, 0.f);
    const float4* w2v = (const float4*)W2;  // pairs of rows: [c0,c1,c0,c1]
    float4 q0 = w2v[4 * lane + 0];
    float4 q1 = w2v[4 * lane + 1];
    float4 q2 = w2v[4 * lane + 2];
    float4 q3 = w2v[4 * lane + 3];
    float p0 = h0 * q0.x + h1 * q0.z + h2 * q1.x + h3 * q1.z +
               h4 * q2.x + h5 * q2.z + h6 * q3.x + h7 * q3.z;
    float p1 = h0 * q0.y + h1 * q0.w + h2 * q1.y + h3 * q1.w +
               h4 * q2.y + h5 * q2.w + h6 * q3.y + h7 * q3.w;
    p0 += __shfl_xor(p0, 1, 4);
    p0 += __shfl_xor(p0, 2, 4);
    p1 += __shfl_xor(p1, 1, 4);
    p1 += __shfl_xor(p1, 2, 4);
    if (lane == 0) {
        float2 o;
        o.x = p0 * d;
        o.y = p1 * d;
        *(float2*)(t2 + node * C) = o;
    }
}

// Layer-2 aggregation + bias + log_softmax. 16 lanes per node.
__global__ void k_agg2(const int* __restrict__ rs, const int* __restrict__ re,
                       const int* __restrict__ colp, const float* __restrict__ t2,
                       const float* __restrict__ dis, const float* __restrict__ b2,
                       float* __restrict__ out) {
    int tid = blockIdx.x * blockDim.x + threadIdx.x;
    int node = tid >> 4;
    if (node >= N) return;
    int lane = tid & 15;
    int start = rs[node], end = re[node];
    float a0 = 0.f, a1 = 0.f;
    for (int idx = start + lane; idx < end; idx += 16) {
        int s = colp[idx];
        float2 v = *(const float2*)(t2 + s * C);
        a0 += v.x;
        a1 += v.y;
    }
#pragma unroll
    for (int off = 8; off > 0; off >>= 1) {
        a0 += __shfl_xor(a0, off, 16);
        a1 += __shfl_xor(a1, off, 16);
    }
    if (lane == 0) {
        float d = dis[node];
        float2 self = *(const float2*)(t2 + node * C);
        float z0 = d * (a0 + self.x) + b2[0];
        float z1 = d * (a1 + self.y) + b2[1];
        float m = fmaxf(z0, z1);
        float l = m + logf(expf(z0 - m) + expf(z1 - m));
        float2 o;
        o.x = z0 - l;
        o.y = z1 - l;
        *(float2*)(out + node * C) = o;
    }
}

extern "C" void kernel_launch(void* const* d_in, const int* in_sizes, int n_in,
                              void* d_out, int out_size, void* d_ws, size_t ws_size,
                              hipStream_t stream) {
    const float* x  = (const float*)d_in[0];
    const int*   ei = (const int*)d_in[1];
    const float* W1 = (const float*)d_in[2];
    const float* b1 = (const float*)d_in[3];
    const float* W2 = (const float*)d_in[4];
    const float* b2 = (const float*)d_in[5];
    float* out = (float*)d_out;

    // Workspace (4B units):
    // epk[NBUCK*CAPB] (reused as t1h after k_csr) | colp[NBUCK*CAPB] |
    // rs[N] | re[N] | dis[N] | t2[N*C] | bcursor[NBUCK] | flag
    int* ws_i = (int*)d_ws;
    int*    epk     = ws_i;
    int*    colp    = epk + (size_t)NBUCK * CAPB;
    int*    rs      = colp + (size_t)NBUCK * CAPB;
    int*    re      = rs + N;
    float*  dis     = (float*)(re + N);
    float*  t2      = (float*)(dis + N);
    int*    bcursor = (int*)(t2 + (size_t)N * C);
    int*    flag    = bcursor + NBUCK;
    __half* t1h     = (__half*)epk;  // N*F halves = 6.4MB <= epk region 8MB

    const int B = 256;
    k_detect<<<1, B, 0, stream>>>(ei, flag, bcursor);
    k_bucket<<<NCHUNK, B, 0, stream>>>(ei, bcursor, epk, flag);
    k_csr<<<NBUCK, 512, 0, stream>>>(epk, bcursor, rs, re, dis, colp);
    k_xw1<<<(N * 32 + B - 1) / B, B, 0, stream>>>(x, W1, dis, t1h);
    k_agg1<<<(N * 4 + B - 1) / B, B, 0, stream>>>(rs, re, colp, t1h, dis, b1, W2, t2);
    k_agg2<<<(N * 16 + B - 1) / B, B, 0, stream>>>(rs, re, colp, t2, dis, b2, out);
}